// Round 1
// 313.254 us; speedup vs baseline: 1.0105x; 1.0105x over previous
//
#include <hip/hip_runtime.h>

// GraphAttention on MI355X (gfx950).  B=2, S=2048, E=1024, H=16, D=64.
// Round 7: attn rewritten around swapped QK^T + in-register P (cvt_pk_bf16 +
// permlane16/32_swap), 32 q-rows per wave (block q-tile 128), double-buffered
// K/V staging with top-of-iter prefetch, vectorized+prefetched bias loads
// (bias pre-scaled by log2e in convert), bijective XCD swizzle.
// qkv/oproj/convert structure unchanged from round 6.

typedef unsigned short ushort_t;
typedef __attribute__((ext_vector_type(8))) short bf16x8;
typedef __attribute__((ext_vector_type(4))) float floatx4;
typedef __attribute__((ext_vector_type(2))) unsigned int uintx2;

#define NB 2
#define NS 2048
#define NE 1024
#define NH 16
#define ND 64
#define LOG2E 1.44269504f

__device__ __forceinline__ unsigned short f2bf(float f) {
  unsigned int u = __float_as_uint(f);
  return (unsigned short)((u + 0x7fffu + ((u >> 16) & 1u)) >> 16);
}
__device__ __forceinline__ float bf2f(unsigned short h) {
  return __uint_as_float(((unsigned int)h) << 16);
}

__device__ __forceinline__ void gload_lds16(const void* g, void* l) {
  __builtin_amdgcn_global_load_lds(
      (const __attribute__((address_space(1))) unsigned int*)g,
      (__attribute__((address_space(3))) unsigned int*)l, 16, 0, 0);
}

__device__ __forceinline__ float fexp2(float x) {
#if __has_builtin(__builtin_amdgcn_exp2f)
  return __builtin_amdgcn_exp2f(x);
#else
  return exp2f(x);
#endif
}

__device__ __forceinline__ unsigned int cvtpk_bf16(float lo, float hi) {
  unsigned int r;
  asm("v_cvt_pk_bf16_f32 %0, %1, %2" : "=v"(r) : "v"(lo), "v"(hi));
  return r;
}

// v_permlane32_swap_b32: dst rows 2,3 <-> src rows 0,1 (rows = 16 lanes)
__device__ __forceinline__ void pl32swap(unsigned int& a, unsigned int& b) {
#if __has_builtin(__builtin_amdgcn_permlane32_swap)
  uintx2 r = __builtin_amdgcn_permlane32_swap(a, b, false, false);
  a = r[0]; b = r[1];
#else
  asm("v_permlane32_swap_b32 %0, %1" : "+v"(a), "+v"(b));
#endif
}
// v_permlane16_swap_b32: dst rows 1,3 <-> src rows 0,2
__device__ __forceinline__ void pl16swap(unsigned int& a, unsigned int& b) {
#if __has_builtin(__builtin_amdgcn_permlane16_swap)
  uintx2 r = __builtin_amdgcn_permlane16_swap(a, b, false, false);
  a = r[0]; b = r[1];
#else
  asm("v_permlane16_swap_b32 %0, %1" : "+v"(a), "+v"(b));
#endif
}

// ---------------------------------------------------------------------------
// Kernel 1: fp32->bf16 conversions + fused (adj, mask) -> bias[b][q][k] bf16.
// Bias is stored pre-scaled by log2(e) so attn uses exp2 directly.
// ---------------------------------------------------------------------------
__global__ __launch_bounds__(256) void convert_kernel(
    const float* __restrict__ q, const float* __restrict__ k, const float* __restrict__ v,
    const float* __restrict__ wq, const float* __restrict__ wk,
    const float* __restrict__ wv, const float* __restrict__ wo,
    const float* __restrict__ adj, const int* __restrict__ mask,
    ushort_t* __restrict__ qb, ushort_t* __restrict__ kb, ushort_t* __restrict__ vb,
    ushort_t* __restrict__ wqb, ushort_t* __restrict__ wkb,
    ushort_t* __restrict__ wvb, ushort_t* __restrict__ wob,
    ushort_t* __restrict__ bias)
{
  const long U1 = (long)NB * NS * NE / 8;  // 524288
  const long U2 = (long)NE * NE / 8;       // 131072
  long idx = (long)blockIdx.x * 256 + threadIdx.x;
  const float* src;
  ushort_t* dst;
  if (idx < U1) { src = q; dst = qb; }
  else if ((idx -= U1) < U1) { src = k; dst = kb; }
  else if ((idx -= U1) < U1) { src = v; dst = vb; }
  else if ((idx -= U1) < U2) { src = wq; dst = wqb; }
  else if ((idx -= U2) < U2) { src = wk; dst = wkb; }
  else if ((idx -= U2) < U2) { src = wv; dst = wvb; }
  else if ((idx -= U2) < U2) { src = wo; dst = wob; }
  else {
    idx -= U2;  // bias unit index in [0, B*S*S/8)
    long flat = idx * 8;
    long rem = flat & ((1L << 22) - 1);
    const float4* a4 = (const float4*)(adj + rem);
    const int4* m4 = (const int4*)(mask + flat);
    float4 a0 = a4[0], a1 = a4[1];
    int4 m0 = m4[0], m1 = m4[1];
    const float NEGV = -1e30f;
    union { ushort_t us[8]; uint4 v4; } o;
    o.us[0] = f2bf((m0.x ? a0.x : NEGV) * LOG2E);
    o.us[1] = f2bf((m0.y ? a0.y : NEGV) * LOG2E);
    o.us[2] = f2bf((m0.z ? a0.z : NEGV) * LOG2E);
    o.us[3] = f2bf((m0.w ? a0.w : NEGV) * LOG2E);
    o.us[4] = f2bf((m1.x ? a1.x : NEGV) * LOG2E);
    o.us[5] = f2bf((m1.y ? a1.y : NEGV) * LOG2E);
    o.us[6] = f2bf((m1.z ? a1.z : NEGV) * LOG2E);
    o.us[7] = f2bf((m1.w ? a1.w : NEGV) * LOG2E);
    ((uint4*)bias)[idx] = o.v4;
    return;
  }
  const float4* s4 = (const float4*)src;
  float4 a0 = s4[idx * 2], a1 = s4[idx * 2 + 1];
  union { ushort_t us[8]; uint4 v4; } o;
  o.us[0] = f2bf(a0.x); o.us[1] = f2bf(a0.y); o.us[2] = f2bf(a0.z); o.us[3] = f2bf(a0.w);
  o.us[4] = f2bf(a1.x); o.us[5] = f2bf(a1.y); o.us[6] = f2bf(a1.z); o.us[7] = f2bf(a1.w);
  ((uint4*)dst)[idx] = o.v4;
}

// ---------------------------------------------------------------------------
// Kernel 2: fused QKV projection GEMM (round-1 proven).
// ---------------------------------------------------------------------------
__global__ __launch_bounds__(256) void qkv_kernel(
    const ushort_t* __restrict__ xq, const ushort_t* __restrict__ xk, const ushort_t* __restrict__ xv,
    const ushort_t* __restrict__ wqb, const ushort_t* __restrict__ wkb, const ushort_t* __restrict__ wvb,
    const float* __restrict__ bq, const float* __restrict__ bk, const float* __restrict__ bvv,
    ushort_t* __restrict__ Qh, ushort_t* __restrict__ Kh, ushort_t* __restrict__ Vt)
{
  __shared__ __align__(16) ushort_t As[128 * 32];
  __shared__ __align__(16) ushort_t Bs[128 * 32];

  int z = blockIdx.z;
  const ushort_t* X = (z == 0) ? xq : (z == 1) ? xk : xv;
  const ushort_t* W = (z == 0) ? wqb : (z == 1) ? wkb : wvb;
  const float* bias = (z == 0) ? bq : (z == 1) ? bk : bvv;

  int t = threadIdx.x;
  int lane = t & 63, w = t >> 6;
  int quad = lane >> 4, l16 = lane & 15;
  int wr = w >> 1, wc = w & 1;
  int m0 = blockIdx.y * 128, f0 = blockIdx.x * 128;

  floatx4 acc[4][4] = {};

  int arow = t >> 2, apart = t & 3;
  const ushort_t* Xg = X + (long)(m0 + arow) * NE + apart * 8;
  const ushort_t* Wg = W + (long)(f0 + arow) * NE + apart * 8;
  ushort_t* As_t = As + t * 8;
  ushort_t* Bs_t = Bs + t * 8;

  for (int k0 = 0; k0 < NE; k0 += 32) {
    __syncthreads();
    gload_lds16(Xg + k0, As_t);
    gload_lds16(Xg + k0 + 64 * NE, As_t + 64 * 32);
    gload_lds16(Wg + k0, Bs_t);
    gload_lds16(Wg + k0 + 64 * NE, Bs_t + 64 * 32);
    __syncthreads();
    bf16x8 af[4], bf[4];
#pragma unroll
    for (int i = 0; i < 4; i++)
      af[i] = *(const bf16x8*)(As + (wr * 64 + i * 16 + l16) * 32 + quad * 8);
#pragma unroll
    for (int j = 0; j < 4; j++)
      bf[j] = *(const bf16x8*)(Bs + (wc * 64 + j * 16 + l16) * 32 + quad * 8);
#pragma unroll
    for (int i = 0; i < 4; i++)
#pragma unroll
      for (int j = 0; j < 4; j++)
        acc[i][j] = __builtin_amdgcn_mfma_f32_16x16x32_bf16(af[i], bf[j], acc[i][j], 0, 0, 0);
  }

  ushort_t* Out = (z == 0) ? Qh : (z == 1) ? Kh : Vt;
  bool isV = (z == 2);
#pragma unroll
  for (int j = 0; j < 4; j++) {
    int f = f0 + wc * 64 + j * 16 + l16;
    float bval = bias[f];
    int h = f >> 6, d = f & 63;
#pragma unroll
    for (int i = 0; i < 4; i++) {
      int mbase = m0 + wr * 64 + i * 16 + quad * 4;
#pragma unroll
      for (int r = 0; r < 4; r++) {
        int m = mbase + r;
        int b = m >> 11, s = m & 2047;
        float y = acc[i][j][r] + bval;
        long off;
        if (!isV) off = ((long)(b * NH + h) * NS + s) * ND + d;       // [B,H,S,D]
        else      off = ((long)(b * NH + h) * ND + d) * NS + s;       // [B,H,D,S]
        Out[off] = f2bf(y);
      }
    }
  }
}

// ---------------------------------------------------------------------------
// Kernel 3: flash attention, max-free, in-register P.
// Block 256 (4 waves), q-tile 128 (32 rows/wave), k-tiles of 32, dbuf K/V.
// Swapped QK^T: sc = mfma(K, Q) -> lane holds P[q=l16][k=jk*16+quad*4+r].
// P -> PV A-frag via v_cvt_pk_bf16_f32 + permlane32/16_swap (no LDS).
// Grid 512 blocks, bijective XCD swizzle co-locates each head's q-blocks.
// ---------------------------------------------------------------------------
__global__ __launch_bounds__(256, 2) void attn_kernel(
    const ushort_t* __restrict__ Qh, const ushort_t* __restrict__ Kh,
    const ushort_t* __restrict__ Vt, const ushort_t* __restrict__ bias,
    ushort_t* __restrict__ aout)
{
  __shared__ __align__(16) ushort_t Qs[128 * 64];    // 16KB (unswizzled)
  __shared__ __align__(16) ushort_t Ks[2][32 * 64];  // 8KB  [row r][chunk c^(r&7)]
  __shared__ __align__(16) ushort_t Vts[2][64 * 32]; // 8KB  [superrow sr][chunk c^(sr&7)]

  int t = threadIdx.x, lane = t & 63, w = t >> 6;
  int quad = lane >> 4, l16 = lane & 15;
  // XCD swizzle: 512 blocks, 64 consecutive wg per XCD -> 4 heads/XCD in L2.
  int orig = blockIdx.y * 16 + blockIdx.x;
  int wg = ((orig & 7) << 6) | (orig >> 3);
  int qt = wg & 15, bh = wg >> 4;
  int bb = bh >> 4, h = bh & 15;
  int q0 = qt * 128;

  // stage Q tile (once): 128 rows x 64 cols
  const ushort_t* Qg = Qh + ((long)bh * NS + q0) * ND;
#pragma unroll
  for (int c = 0; c < 4; c++) {
    int idx = c * 256 + t;
    gload_lds16(Qg + (long)(idx >> 3) * ND + (idx & 7) * 8, Qs + idx * 8);
  }

  const ushort_t* Kg = Kh + (long)bh * NS * ND;
  const ushort_t* Vg = Vt + (long)bh * ND * NS;
  // K staging: thread t -> LDS chunk t. row = t>>3, dest chunk c' = t&7,
  // source chunk c = c' ^ (row&7).
  int krow = t >> 3;
  int kc = (t & 7) ^ (krow & 7);
  // V staging: superrow sr = t>>3 (2 d-rows), source chunk c = (t&7)^(sr&7).
  int vsr = t >> 3;
  int vc = (t & 7) ^ (vsr & 7);
  int vrow = vsr * 2 + (vc >> 2);
  int vpart = vc & 3;
  const ushort_t* Kgp = Kg + (long)krow * ND + kc * 8;    // +32*ND per kt
  const ushort_t* Vgp = Vg + (long)vrow * NS + vpart * 8; // +32 per kt

  // stage k-tile 0 into buffer 0
  gload_lds16(Kgp, &Ks[0][t * 8]);
  gload_lds16(Vgp, &Vts[0][t * 8]);

  // bias: lane covers rows q = q0 + w*32 + m*16 + l16, cols quad*4 + jk*16
  const ushort_t* bg0 = bias + (long)bb * NS * NS
                      + (long)(q0 + w * 32 + l16) * NS + quad * 4;
  const ushort_t* bg1 = bg0 + 16 * NS;
  uintx2 bc[2][2];
  bc[0][0] = *(const uintx2*)bg0;
  bc[0][1] = *(const uintx2*)(bg0 + 16);
  bc[1][0] = *(const uintx2*)bg1;
  bc[1][1] = *(const uintx2*)(bg1 + 16);

  __syncthreads();

  bf16x8 aq[2][2];
#pragma unroll
  for (int m = 0; m < 2; m++)
#pragma unroll
    for (int kd = 0; kd < 2; kd++)
      aq[m][kd] = *(const bf16x8*)(Qs + (w * 32 + m * 16 + l16) * 64 + kd * 32 + quad * 8);

  floatx4 acc[2][4] = {};
  float lsum[2] = {0.f, 0.f};

  const int ks_x = l16 & 7;
  const int vs_c = (((l16 & 1) * 4 + quad) ^ (l16 >> 1)) * 8;

#pragma unroll 2
  for (int kt = 0; kt < NS / 32; kt++) {
    int cur = kt & 1;
    __syncthreads();  // buf[cur] staged; all prior reads of buf[cur^1] done
    if (kt < NS / 32 - 1) {
      // prefetch next k-tile into the other buffer (in flight over the body)
      gload_lds16(Kgp + (long)(kt + 1) * (32 * ND), &Ks[cur ^ 1][t * 8]);
      gload_lds16(Vgp + (kt + 1) * 32, &Vts[cur ^ 1][t * 8]);
    }
    // prefetch next tile's bias into registers
    uintx2 bn[2][2];
#pragma unroll
    for (int m = 0; m < 2; m++) { bn[m][0] = bc[m][0]; bn[m][1] = bc[m][1]; }
    if (kt < NS / 32 - 1) {
      bn[0][0] = *(const uintx2*)(bg0 + (kt + 1) * 32);
      bn[0][1] = *(const uintx2*)(bg0 + (kt + 1) * 32 + 16);
      bn[1][0] = *(const uintx2*)(bg1 + (kt + 1) * 32);
      bn[1][1] = *(const uintx2*)(bg1 + (kt + 1) * 32 + 16);
    }

    const ushort_t* Kb = Ks[cur];
    const ushort_t* Vb = Vts[cur];
    bf16x8 bk[2][2], bv[4];
#pragma unroll
    for (int jk = 0; jk < 2; jk++)
#pragma unroll
      for (int kd = 0; kd < 2; kd++)
        bk[jk][kd] = *(const bf16x8*)(Kb + (jk * 16 + l16) * 64
                                         + ((kd * 4 + quad) ^ ks_x) * 8);
#pragma unroll
    for (int j = 0; j < 4; j++)
      bv[j] = *(const bf16x8*)(Vb + (j * 8 + (l16 >> 1)) * 64 + vs_c);

#pragma unroll
    for (int m = 0; m < 2; m++) {
      // swapped scores: sc[jk] rows = k (quad*4+r), cols = q (l16)
      floatx4 sc[2] = {};
#pragma unroll
      for (int jk = 0; jk < 2; jk++)
#pragma unroll
        for (int kd = 0; kd < 2; kd++)
          sc[jk] = __builtin_amdgcn_mfma_f32_16x16x32_bf16(bk[jk][kd], aq[m][kd], sc[jk], 0, 0, 0);

      // p = exp2(sc * 0.125*log2e + bias_prescaled)
      float p[2][4];
#pragma unroll
      for (int jk = 0; jk < 2; jk++) {
        unsigned int d0 = bc[m][jk][0], d1 = bc[m][jk][1];
        float b0 = __uint_as_float(d0 << 16);
        float b1 = __uint_as_float(d0 & 0xffff0000u);
        float b2 = __uint_as_float(d1 << 16);
        float b3 = __uint_as_float(d1 & 0xffff0000u);
        p[jk][0] = fexp2(fmaf(sc[jk][0], 0.125f * LOG2E, b0));
        p[jk][1] = fexp2(fmaf(sc[jk][1], 0.125f * LOG2E, b1));
        p[jk][2] = fexp2(fmaf(sc[jk][2], 0.125f * LOG2E, b2));
        p[jk][3] = fexp2(fmaf(sc[jk][3], 0.125f * LOG2E, b3));
      }
      lsum[m] += ((p[0][0] + p[0][1]) + (p[0][2] + p[0][3]))
               + ((p[1][0] + p[1][1]) + (p[1][2] + p[1][3]));

      // pack k-adjacent pairs, redistribute across quads to PV A-frag:
      // after pl32+pl16: A0 = F0 {A0q0,A0q2,B0q0,B0q2}, B0 = F2 {A0q1,A0q3,B0q1,B0q3}
      unsigned int A0 = cvtpk_bf16(p[0][0], p[0][1]);
      unsigned int A1 = cvtpk_bf16(p[0][2], p[0][3]);
      unsigned int B0 = cvtpk_bf16(p[1][0], p[1][1]);
      unsigned int B1 = cvtpk_bf16(p[1][2], p[1][3]);
      pl32swap(A0, B0); pl16swap(A0, B0);
      pl32swap(A1, B1); pl16swap(A1, B1);
      union { unsigned int u[4]; bf16x8 v8; } pf;
      pf.u[0] = A0; pf.u[1] = A1; pf.u[2] = B0; pf.u[3] = B1;
#pragma unroll
      for (int j = 0; j < 4; j++)
        acc[m][j] = __builtin_amdgcn_mfma_f32_16x16x32_bf16(pf.v8, bv[j], acc[m][j], 0, 0, 0);
    }
#pragma unroll
    for (int m = 0; m < 2; m++) { bc[m][0] = bn[m][0]; bc[m][1] = bn[m][1]; }
  }

  // row-sum: lane holds partial for q = l16 (per m); reduce across quads
#pragma unroll
  for (int m = 0; m < 2; m++) {
    float s = lsum[m];
    s += __shfl_xor(s, 16);
    s += __shfl_xor(s, 32);
    lsum[m] = s;
  }

  // epilogue: O / l -> aout [B,S,E] bf16.  acc rows: q = w*32+m*16+quad*4+r
  ushort_t* og = aout + (long)bb * NS * NE + h * ND;
#pragma unroll
  for (int m = 0; m < 2; m++)
#pragma unroll
    for (int r = 0; r < 4; r++) {
      float inv = 1.0f / __shfl(lsum[m], quad * 4 + r);
      int qg = q0 + w * 32 + m * 16 + quad * 4 + r;
#pragma unroll
      for (int j = 0; j < 4; j++)
        og[(long)qg * NE + j * 16 + l16] = f2bf(acc[m][j][r] * inv);
    }
}

// ---------------------------------------------------------------------------
// Kernel 4: output projection. out = aout @ Wo^T + bo, fp32 stores.
// 128m x 64n tiles, grid (16, 32) = 512 blocks = 2/CU.
// ---------------------------------------------------------------------------
__global__ __launch_bounds__(256) void oproj_kernel(
    const ushort_t* __restrict__ A, const ushort_t* __restrict__ Wob,
    const float* __restrict__ bo, float* __restrict__ out)
{
  __shared__ __align__(16) ushort_t As[128 * 32];  // 8KB
  __shared__ __align__(16) ushort_t Bs[64 * 32];   // 4KB

  int t = threadIdx.x;
  int lane = t & 63, w = t >> 6;
  int quad = lane >> 4, l16 = lane & 15;
  int wr = w >> 1, wc = w & 1;
  int m0 = blockIdx.y * 128, f0 = blockIdx.x * 64;

  floatx4 acc[4][2] = {};
  int arow = t >> 2, apart = t & 3;
  const ushort_t* Xg = A + (long)(m0 + arow) * NE + apart * 8;
  const ushort_t* Wg = Wob + (long)(f0 + arow) * NE + apart * 8;
  ushort_t* As_t = As + t * 8;
  ushort_t* Bs_t = Bs + t * 8;
  bool bstage = (arow < 64);

  for (int k0 = 0; k0 < NE; k0 += 32) {
    __syncthreads();
    gload_lds16(Xg + k0, As_t);
    gload_lds16(Xg + k0 + 64 * NE, As_t + 64 * 32);
    if (bstage) gload_lds16(Wg + k0, Bs_t);
    __syncthreads();
    bf16x8 af[4], bf[2];
#pragma unroll
    for (int i = 0; i < 4; i++)
      af[i] = *(const bf16x8*)(As + (wr * 64 + i * 16 + l16) * 32 + quad * 8);
#pragma unroll
    for (int j = 0; j < 2; j++)
      bf[j] = *(const bf16x8*)(Bs + (wc * 32 + j * 16 + l16) * 32 + quad * 8);
#pragma unroll
    for (int i = 0; i < 4; i++)
#pragma unroll
      for (int j = 0; j < 2; j++)
        acc[i][j] = __builtin_amdgcn_mfma_f32_16x16x32_bf16(af[i], bf[j], acc[i][j], 0, 0, 0);
  }

#pragma unroll
  for (int j = 0; j < 2; j++) {
    int f = f0 + wc * 32 + j * 16 + l16;
    float bval = bo[f];
#pragma unroll
    for (int i = 0; i < 4; i++) {
      int mbase = m0 + wr * 64 + i * 16 + quad * 4;
#pragma unroll
      for (int r = 0; r < 4; r++) {
        int m = mbase + r;
        out[(long)m * NE + f] = acc[i][j][r] + bval;
      }
    }
  }
}

// ---------------------------------------------------------------------------
extern "C" void kernel_launch(void* const* d_in, const int* in_sizes, int n_in,
                              void* d_out, int out_size, void* d_ws, size_t ws_size,
                              hipStream_t stream) {
  const float* query = (const float*)d_in[0];
  const float* key   = (const float*)d_in[1];
  const float* value = (const float*)d_in[2];
  const float* adj   = (const float*)d_in[3];
  const int*   mask  = (const int*)d_in[4];
  const float* Wq = (const float*)d_in[5];
  const float* bq = (const float*)d_in[6];
  const float* Wk = (const float*)d_in[7];
  const float* bk = (const float*)d_in[8];
  const float* Wv = (const float*)d_in[9];
  const float* bv = (const float*)d_in[10];
  const float* Wo = (const float*)d_in[11];
  const float* bo = (const float*)d_in[12];
  float* out = (float*)d_out;

  char* ws = (char*)d_ws;
  const size_t MB = 1ull << 20;
  ushort_t* qb   = (ushort_t*)(ws + 0 * MB);    // 8 MiB  [B*S, E] bf16
  ushort_t* kb   = (ushort_t*)(ws + 8 * MB);    // 8 MiB
  ushort_t* vb   = (ushort_t*)(ws + 16 * MB);   // 8 MiB
  ushort_t* wqb  = (ushort_t*)(ws + 24 * MB);   // 2 MiB  [E,E] bf16
  ushort_t* wkb  = (ushort_t*)(ws + 26 * MB);   // 2 MiB
  ushort_t* wvb  = (ushort_t*)(ws + 28 * MB);   // 2 MiB
  ushort_t* wob  = (ushort_t*)(ws + 30 * MB);   // 2 MiB
  ushort_t* Qh   = (ushort_t*)(ws + 32 * MB);   // 8 MiB  [B,H,S,D]
  ushort_t* Kh   = (ushort_t*)(ws + 40 * MB);   // 8 MiB  [B,H,S,D]
  ushort_t* Vt   = (ushort_t*)(ws + 48 * MB);   // 8 MiB  [B,H,D,S]
  ushort_t* aout = (ushort_t*)(ws + 56 * MB);   // 8 MiB  [B,S,E]
  ushort_t* bias = (ushort_t*)(ws + 64 * MB);   // 16 MiB [B,S,S] (pre-scaled by log2e)

  convert_kernel<<<12288, 256, 0, stream>>>(query, key, value, Wq, Wk, Wv, Wo,
                                            adj, mask, qb, kb, vb, wqb, wkb, wvb, wob, bias);
  qkv_kernel<<<dim3(8, 32, 3), 256, 0, stream>>>(qb, kb, vb, wqb, wkb, wvb,
                                                 bq, bk, bv, Qh, Kh, Vt);
  attn_kernel<<<dim3(16, 32), 256, 0, stream>>>(Qh, Kh, Vt, bias, aout);
  oproj_kernel<<<dim3(16, 32), 256, 0, stream>>>(aout, wob, bo, out);
}